// Round 10
// baseline (33.667 us; speedup 1.0000x reference)
//
#include <hip/hip_runtime.h>
#include <hip/hip_bf16.h>
#include <math.h>

#define D_IN  128
#define NH    8
#define F_OUT 32
#define HID   256
#define D_EMB 64
#define BINS  200
#define FDIM  384
#define CAP   128
#define SLOTS 6
#define SNF   48     // matched-edge nf rows staged in LDS (cnt~32 expected)

#define NSTAGE 32
#define NSCANB 219
#define VSRC_B 219   // 8 blocks : vsrc + strg
#define SKIP_B 227   // 8 blocks : skipb
#define ESC_B  235   // 4 blocks : escall
#define SMS_B  239   // 1 block  : sms
#define PRE1_B 240   // 16 blocks: pre1 -> 256
#define GRID   256

#define AR __ATOMIC_RELAXED
#define SA __HIP_MEMORY_SCOPE_AGENT
#define STF(p, v) __hip_atomic_store((p), (v), AR, SA)
#define LDF(p)    __hip_atomic_load((p), AR, SA)

// ---- ws layout ----
// ints: [0]=flag_mlp ; ready[256] @+16 ; done_proj[32] @+288 ;
//       btrg[1314] @+512 ; bbin[1314] @+2048
// floats (fb = (float*)d_ws + 8192):
//   vsrc[1024] strg[16]@1024 sms[8]@1040 escall[1600]@1048 skipb[512]@2648
//   pre1[256]@3160 out_ws[512]@3416 partial[32]@3928 ; bnf @4096 (219*6*128)

__device__ __forceinline__ float redw(float v) {
#pragma unroll
  for (int o = 32; o > 0; o >>= 1) v += __shfl_down(v, o, 64);
  return v;
}

__device__ __forceinline__ void vm0() {
  asm volatile("s_waitcnt vmcnt(0)" ::: "memory");
}

__global__ void zero_k(int* ws_i) { ws_i[threadIdx.x] = 0; }

// scan a slice into private slots, publish via STF, then mark ready[bid]=c+1
__device__ __forceinline__ void scan_block(
    const int* __restrict__ etrg, const int* __restrict__ esrc,
    const int* __restrict__ ebin, const float* __restrict__ nf,
    int bid, int tid, int nE, int li, int ld,
    int* l_cnt, int* l_src, int* l_trg, int* l_bin,
    int* btrg, int* bbin, float* bnf, int* ready) {
  if (tid == 0) *l_cnt = 0;
  __syncthreads();
  const int gid = bid * 512 + tid;
  const int stride = NSCANB * 512;
  const int nE4 = nE >> 2;
  const int4* t4 = (const int4*)etrg;
  for (int e4 = gid; e4 < nE4; e4 += stride) {
    int4 t = t4[e4];
    int ev[4] = {t.x, t.y, t.z, t.w};
#pragma unroll
    for (int kk = 0; kk < 4; ++kk) {
      if (ev[kk] == li || ev[kk] == ld) {
        int e = e4 * 4 + kk;
        int p = atomicAdd(l_cnt, 1);
        if (p < SLOTS) { l_src[p] = esrc[e]; l_trg[p] = ev[kk]; l_bin[p] = ebin[e]; }
      }
    }
  }
  if (bid == 0 && tid == 0) {          // tail (nE % 4)
    for (int e = nE4 * 4; e < nE; ++e) {
      int tv = etrg[e];
      if (tv == li || tv == ld) {
        int p = atomicAdd(l_cnt, 1);
        if (p < SLOTS) { l_src[p] = esrc[e]; l_trg[p] = tv; l_bin[p] = ebin[e]; }
      }
    }
  }
  __syncthreads();
  int c = *l_cnt; if (c > SLOTS) c = SLOTS;
  if (tid < c) {
    STF(btrg + bid * SLOTS + tid, l_trg[tid]);
    STF(bbin + bid * SLOTS + tid, l_bin[tid]);
  }
  const int wv = tid >> 6, ln = tid & 63;
  if (wv < c)
    for (int j = ln; j < D_IN; j += 64)
      STF(bnf + (size_t)(bid * SLOTS + wv) * D_IN + j,
          nf[(size_t)l_src[wv] * D_IN + j]);
  vm0();
  __syncthreads();
  if (tid == 0) STF(ready + bid, c + 1);
}

__global__ __launch_bounds__(512, 1) void fused_k(
    const float* __restrict__ nf, const int* __restrict__ esrc,
    const int* __restrict__ etrg, const int* __restrict__ ebin,
    const float* __restrict__ ms, const int* __restrict__ li_p,
    const int* __restrict__ ld_p, const int* __restrict__ dist_p,
    const float* __restrict__ Wproj, const float* __restrict__ a_src,
    const float* __restrict__ a_trg, const float* __restrict__ Wms,
    const float* __restrict__ demb_g, const float* __restrict__ Wdist,
    const float* __restrict__ Wskip, const float* __restrict__ gbias,
    const float* __restrict__ demb_h, const float* __restrict__ W1,
    const float* __restrict__ b1, const float* __restrict__ W2,
    const float* __restrict__ b2, int nE,
    int* __restrict__ ws_i, float* __restrict__ fb, float* __restrict__ out) {
  int* flag_mlp  = ws_i;
  int* ready     = ws_i + 16;
  int* done_proj = ws_i + 288;
  int* btrg      = ws_i + 512;
  int* bbin      = ws_i + 2048;
  float* vsrc    = fb;
  float* strg    = fb + 1024;
  float* sms     = fb + 1040;
  float* escall  = fb + 1048;
  float* skipb   = fb + 2648;
  float* pre1    = fb + 3160;
  float* out_ws  = fb + 3416;
  float* partial = fb + 3928;
  float* bnf     = fb + 4096;

  __shared__ int l_cnt;
  __shared__ int l_src[SLOTS], l_trg[SLOTS], l_bin[SLOTS];
  __shared__ int s_bc[256], s_sc[256];
  __shared__ int s_sl[CAP], s_tb[CAP], s_bn[CAP];
  __shared__ float s_p[CAP];
  __shared__ float s_den[2];
  __shared__ __align__(16) float s_vs[D_IN];
  __shared__ __align__(16) float s_bnf[SNF * D_IN];     // 24 KB
  __shared__ __align__(16) float s_agg[2][D_IN];
  __shared__ __align__(16) float s_out[512];
  __shared__ __align__(16) float s_emb[64];
  __shared__ float s_pr[8];
  __shared__ __align__(16) float s_nf2[2 * D_IN];
  __shared__ __align__(16) float s_vp[2][4][D_IN];

  const int bid = blockIdx.x, tid = threadIdx.x;
  const int wv = tid >> 6, ln = tid & 63;
  const int li = li_p[0], ld = ld_p[0];

  if (bid < NSTAGE) {
    // ===================== STAGE: scan slice, then finalize =====================
    const int k = bid;
    const int h = k >> 2;
    const int row = k * 8 + wv;
    // read-only preloads, issued before/while scanning
    const float wpA = Wproj[row * D_IN + ln * 2];
    const float wpB = Wproj[row * D_IN + ln * 2 + 1];
    const float w1e = W1[(size_t)row * FDIM + HID + ln];
    const float w2v = W2[row];

    scan_block(etrg, esrc, ebin, nf, bid, tid, nE, li, ld,
               &l_cnt, l_src, l_trg, l_bin, btrg, bbin, bnf, ready);

    // ---- poll all 256 ready words (read-spin, distinct words) ----
    if (tid < 256) {
      int v;
      for (;;) { v = LDF(ready + tid); if (v) break; __builtin_amdgcn_s_sleep(1); }
      s_bc[tid] = (tid < NSCANB) ? (v - 1) : 0;
    }
    __syncthreads();

    // ---- deterministic compaction: inclusive prefix scan over 256 counts ----
    if (tid < 256) s_sc[tid] = s_bc[tid];
    __syncthreads();
    for (int off = 1; off < 256; off <<= 1) {
      int v = 0;
      if (tid < 256 && tid >= off) v = s_sc[tid - off];
      __syncthreads();
      if (tid < 256) s_sc[tid] += v;
      __syncthreads();
    }
    int cnt = s_sc[255]; if (cnt > CAP) cnt = CAP;
    if (tid < NSCANB) {
      int c = s_bc[tid], base = s_sc[tid] - c;
      for (int j = 0; j < c; ++j)
        if (base + j < CAP) s_sl[base + j] = tid * SLOTS + j;
    }
    __syncthreads();

    // ---- metadata + vsrc ----
    if (tid < cnt) {
      int sl = s_sl[tid];
      s_tb[tid] = (LDF(btrg + sl) == li) ? 0 : 1;
      s_bn[tid] = LDF(bbin + sl);
    }
    if (tid < D_IN) s_vs[tid] = LDF(vsrc + h * D_IN + tid);
    __syncthreads();

    // ---- stage matched nf rows to LDS ----
    const int nl = (cnt < SNF ? cnt : SNF) * D_IN;
    for (int idx = tid; idx < nl; idx += 512)
      s_bnf[idx] = LDF(bnf + (size_t)s_sl[idx >> 7] * D_IN + (idx & 127));
    __syncthreads();

    // ---- scores: exp(leaky_relu(.)); global max cancels in exp_s/denom ----
    const float sms_h = LDF(sms + h);
    const float strg0 = LDF(strg + h), strg1 = LDF(strg + NH + h);
    for (int e = wv; e < cnt; e += 8) {
      float x0, x1;
      if (e < SNF) { x0 = s_bnf[e * D_IN + ln * 2]; x1 = s_bnf[e * D_IN + ln * 2 + 1]; }
      else {
        const float* g = bnf + (size_t)s_sl[e] * D_IN + ln * 2;
        x0 = LDF(g); x1 = LDF(g + 1);
      }
      float part = redw(x0 * s_vs[ln * 2] + x1 * s_vs[ln * 2 + 1]);
      if (ln == 0) {
        float sc = part + (s_tb[e] ? strg1 : strg0) + sms_h + LDF(escall + s_bn[e] * NH + h);
        sc = sc > 0.f ? sc : 0.2f * sc;
        s_p[e] = expf(sc);
      }
    }
    __syncthreads();
    if (tid < 2) {
      float d = 1e-16f;
      for (int e = 0; e < cnt; ++e) if (s_tb[e] == (int)tid) d += s_p[e];
      s_den[tid] = d;
    }
    __syncthreads();
    if (tid < cnt) s_p[tid] = s_p[tid] / s_den[s_tb[tid]];
    __syncthreads();
    if (tid < 256) {                        // agg[t,d] for head h
      const int t = tid >> 7, d = tid & 127;
      float a = 0.f;
      for (int e = 0; e < cnt; ++e) {
        if (s_tb[e] == t) {
          float v = (e < SNF) ? s_bnf[e * D_IN + d]
                              : LDF(bnf + (size_t)s_sl[e] * D_IN + d);
          a = fmaf(s_p[e], v, a);
        }
      }
      s_agg[t][d] = a;
    }
    __syncthreads();
    {
      float o0 = wpA * s_agg[0][ln * 2] + wpB * s_agg[0][ln * 2 + 1];
      float o1 = wpA * s_agg[1][ln * 2] + wpB * s_agg[1][ln * 2 + 1];
      o0 = redw(o0); o1 = redw(o1);
      if (ln == 0) {
        STF(out_ws + row,       o0 + LDF(skipb + row));
        STF(out_ws + 256 + row, o1 + LDF(skipb + 256 + row));
      }
    }
    // ---- proj handoff: per-block done markers, read-spin ----
    vm0();
    __syncthreads();
    if (tid == 0) STF(done_proj + k, 1);
    if (tid < NSTAGE)
      while (LDF(done_proj + tid) == 0) __builtin_amdgcn_s_sleep(1);
    __syncthreads();

    // ---- MLP ----
    s_out[tid] = LDF(out_ws + tid);
    __syncthreads();
    if (tid < 64) {
      const int t = tid >> 5, f = tid & 31;
      float s = 0.f;
#pragma unroll
      for (int hh = 0; hh < NH; ++hh) s += s_out[t * 256 + hh * F_OUT + f];
      s = s * 0.125f + gbias[f];
      s_emb[tid] = s > 0.f ? s : expm1f(s);  // ELU
    }
    __syncthreads();
    {
      float acc = redw(w1e * s_emb[ln]);
      if (ln == 0) {
        float h1 = fmaxf(LDF(pre1 + row) + acc, 0.f);
        s_pr[wv] = w2v * h1;
      }
    }
    __syncthreads();
    if (tid == 0) {
      float bp = 0.f;
#pragma unroll
      for (int w = 0; w < 8; ++w) bp += s_pr[w];
      STF(partial + k, bp);
      vm0();
      int ret = __hip_atomic_fetch_add(flag_mlp, 1, AR, SA);
      if (ret == NSTAGE - 1) {               // last block finalizes
        float s = b2[0];
        for (int j = 0; j < NSTAGE; ++j) s += LDF(partial + j);
        out[0] = s;
      }
    }
    return;
  }

  if (bid < NSCANB) {
    // ===== scan-only =====
    scan_block(etrg, esrc, ebin, nf, bid, tid, nE, li, ld,
               &l_cnt, l_src, l_trg, l_bin, btrg, bbin, bnf, ready);
    return;
  }

  // ===================== pre-task blocks =====================
  if (bid < SKIP_B) {
    // ===== vsrc + strg for head h =====
    const int h = bid - VSRC_B;
    const int d = tid & 127, fg = tid >> 7;
    float as = 0.f, at = 0.f;
    for (int f = fg * 8; f < fg * 8 + 8; ++f) {
      float w = Wproj[(h * F_OUT + f) * D_IN + d];
      as = fmaf(a_src[h * F_OUT + f], w, as);
      at = fmaf(a_trg[h * F_OUT + f], w, at);
    }
    s_vp[0][fg][d] = as; s_vp[1][fg][d] = at;
    __syncthreads();
    if (tid < 128)
      STF(vsrc + h * D_IN + tid,
          s_vp[0][0][tid] + s_vp[0][1][tid] + s_vp[0][2][tid] + s_vp[0][3][tid]);
    if (tid >= 128 && tid < 256) {
      int dd = tid - 128;
      s_vp[1][0][dd] = s_vp[1][0][dd] + s_vp[1][1][dd] + s_vp[1][2][dd] + s_vp[1][3][dd];
    }
    if (tid >= 256 && tid < 320) {
      int j = tid - 256;
      ((float4*)s_nf2)[j] = ((const float4*)(nf + (size_t)(j < 32 ? li : ld) * D_IN))[j & 31];
    }
    __syncthreads();
    if (wv < 2) {   // strg[t,h] = nf2[t] . vtrg[h]
      float part = s_nf2[wv * D_IN + ln * 2] * s_vp[1][0][ln * 2]
                 + s_nf2[wv * D_IN + ln * 2 + 1] * s_vp[1][0][ln * 2 + 1];
      part = redw(part);
      if (ln == 0) STF(strg + wv * NH + h, part);
    }
  } else if (bid < ESC_B) {
    // ===== skipb rows [32p, 32p+32) =====
    const int base = (bid - SKIP_B) * 32;
    if (tid < 64)
      ((float4*)s_nf2)[tid] = ((const float4*)(nf + (size_t)(tid < 32 ? li : ld) * D_IN))[tid & 31];
    __syncthreads();
    for (int rd = 0; rd < 4; ++rd) {
      int r = base + rd * 8 + wv;
      float w0 = Wskip[r * D_IN + ln * 2], w1 = Wskip[r * D_IN + ln * 2 + 1];
      float o0 = w0 * s_nf2[ln * 2] + w1 * s_nf2[ln * 2 + 1];
      float o1 = w0 * s_nf2[D_IN + ln * 2] + w1 * s_nf2[D_IN + ln * 2 + 1];
      o0 = redw(o0); o1 = redw(o1);
      if (ln == 0) { STF(skipb + r, o0); STF(skipb + 256 + r, o1); }
    }
  } else if (bid < SMS_B) {
    // ===== escall bins [50p, 50p+50) =====
    const int p = bid - ESC_B;
    const int g = tid >> 3, l8 = tid & 7;
    for (int it = g; it < 50 * NH; it += 64) {
      int bin = p * 50 + (it >> 3), hh = it & 7;
      const float* de = demb_g + bin * D_EMB + l8 * 8;
      const float* wd = Wdist + hh * D_EMB + l8 * 8;
      float a = 0.f;
#pragma unroll
      for (int j = 0; j < 8; ++j) a = fmaf(de[j], wd[j], a);
#pragma unroll
      for (int o = 4; o > 0; o >>= 1) a += __shfl_down(a, o, 8);
      if (l8 == 0) STF(escall + bin * NH + hh, a);
    }
  } else if (bid < PRE1_B) {
    // ===== sms[h] = Wms[h] . ms (wave per head) =====
    const float* wr = Wms + wv * HID;
    float a = 0.f;
#pragma unroll
    for (int m = 0; m < 4; ++m) a = fmaf(wr[ln + 64 * m], ms[ln + 64 * m], a);
    a = redw(a);
    if (ln == 0) STF(sms + wv, a);
  } else {
    // ===== pre1 rows [16q, 16q+16) =====
    const int q = bid - PRE1_B;
    const int dist = dist_p[0];
    for (int rr = 0; rr < 2; ++rr) {
      int r = q * 16 + wv * 2 + rr;
      const float* w = W1 + (size_t)r * FDIM;
      float a = 0.f;
#pragma unroll
      for (int m = 0; m < 4; ++m) a = fmaf(w[ln + 64 * m], ms[ln + 64 * m], a);
      a = fmaf(w[320 + ln], demb_h[(size_t)dist * D_EMB + ln], a);
      a = redw(a);
      if (ln == 0) STF(pre1 + r, a + b1[r]);
    }
  }
  // pre blocks: publish ready marker
  vm0();
  __syncthreads();
  if (tid == 0) STF(ready + bid, 1);
}

extern "C" void kernel_launch(void* const* d_in, const int* in_sizes, int n_in,
                              void* d_out, int out_size, void* d_ws, size_t ws_size,
                              hipStream_t stream) {
  const float* nf     = (const float*)d_in[0];
  const int*   esrc   = (const int*)d_in[1];
  const int*   etrg   = (const int*)d_in[2];
  const int*   ebin   = (const int*)d_in[3];
  const float* ms     = (const float*)d_in[4];
  const int*   li_p   = (const int*)d_in[5];
  const int*   ld_p   = (const int*)d_in[6];
  const int*   dist_p = (const int*)d_in[7];
  const float* Wproj  = (const float*)d_in[8];
  const float* a_src  = (const float*)d_in[9];
  const float* a_trg  = (const float*)d_in[10];
  const float* Wms    = (const float*)d_in[11];
  const float* demb_g = (const float*)d_in[12];
  const float* Wdist  = (const float*)d_in[13];
  const float* Wskip  = (const float*)d_in[14];
  const float* gbias  = (const float*)d_in[15];
  const float* demb_h = (const float*)d_in[16];
  const float* W1     = (const float*)d_in[17];
  const float* b1     = (const float*)d_in[18];
  const float* W2     = (const float*)d_in[19];
  const float* b2     = (const float*)d_in[20];
  const int nE = in_sizes[1];

  int*   ws_i = (int*)d_ws;
  float* fb   = (float*)d_ws + 8192;

  zero_k<<<1, 512, 0, stream>>>(ws_i);

  fused_k<<<GRID, 512, 0, stream>>>(
      nf, esrc, etrg, ebin, ms, li_p, ld_p, dist_p,
      Wproj, a_src, a_trg, Wms, demb_g, Wdist, Wskip, gbias, demb_h,
      W1, b1, W2, b2, nE, ws_i, fb, (float*)d_out);
}

// Round 11
// 27.096 us; speedup vs baseline: 1.2425x; 1.2425x over previous
//
#include <hip/hip_runtime.h>
#include <hip/hip_bf16.h>
#include <math.h>

#define D_IN  128
#define NH    8
#define F_OUT 32
#define HID   256
#define D_EMB 64
#define BINS  200
#define FDIM  384
#define CAP   128
#define SLOTS 6
#define SNF   64     // matched-edge nf rows staged in K2 LDS (cnt~32 expected)
#define NSLOT (219 * SLOTS)   // 1314

// ---- K1 grid (256 blocks): 219 scan + 37 pre ----
#define NSCANB 219
#define VSRC_B 219   // 8 blocks : vsrc + strg (h==0 also zeroes K2 flags)
#define SKIP_B 227   // 8 blocks : skipb
#define ESC_B  235   // 4 blocks : escall
#define SMS_B  239   // 1 block  : sms
#define PRE1_B 240   // 16 blocks: pre1 -> 256
#define K1GRID 256
#define K2GRID 8     // one block per head

#define AR __ATOMIC_RELAXED
#define SA __HIP_MEMORY_SCOPE_AGENT
#define STF(p, v) __hip_atomic_store((p), (v), AR, SA)
#define LDF(p)    __hip_atomic_load((p), AR, SA)

// ---- ws layout ----
// ints (ws_i): [0]=flag_mlp ; done_proj[8] @+8 ; bcnt[219] @+16 ;
//              bsrc @+256 ; btrg @+1600 ; bbin @+2944
// floats (fb = (float*)d_ws + 8192):
//   vsrc[1024] strg[16]@1024 sms[8]@1040 escall[1600]@1048 skipb[512]@2648
//   pre1[256]@3160 out_ws[512]@3416 partial[32]@3928 ; bnf @4096 (219*6*128)

__device__ __forceinline__ float redw(float v) {
#pragma unroll
  for (int o = 32; o > 0; o >>= 1) v += __shfl_down(v, o, 64);
  return v;
}

__device__ __forceinline__ void vm0() {
  asm volatile("s_waitcnt vmcnt(0)" ::: "memory");
}

// =====================================================================
// K1: edge scan (private per-block slots) + pre-tasks. Plain stores only;
// the kernel boundary (end-of-kernel L2 writeback) publishes to K2.
// =====================================================================
__global__ __launch_bounds__(512, 1) void scan_pre_k(
    const float* __restrict__ nf, const int* __restrict__ esrc,
    const int* __restrict__ etrg, const int* __restrict__ ebin,
    const float* __restrict__ ms, const int* __restrict__ li_p,
    const int* __restrict__ ld_p, const int* __restrict__ dist_p,
    const float* __restrict__ Wproj, const float* __restrict__ a_src,
    const float* __restrict__ a_trg, const float* __restrict__ Wms,
    const float* __restrict__ demb_g, const float* __restrict__ Wdist,
    const float* __restrict__ Wskip, const float* __restrict__ W1,
    const float* __restrict__ b1, const float* __restrict__ demb_h,
    int nE, int* __restrict__ ws_i, float* __restrict__ fb) {
  int* bcnt = ws_i + 16;
  int* bsrc = ws_i + 256;
  int* btrg = ws_i + 1600;
  int* bbin = ws_i + 2944;
  float* vsrc   = fb;
  float* strg   = fb + 1024;
  float* sms    = fb + 1040;
  float* escall = fb + 1048;
  float* skipb  = fb + 2648;
  float* pre1   = fb + 3160;
  float* bnf    = fb + 4096;

  __shared__ __align__(16) float s_nf2[2 * D_IN];
  __shared__ __align__(16) float s_vp[2][4][D_IN];
  __shared__ int l_cnt;
  __shared__ int l_src[SLOTS], l_trg[SLOTS], l_bin[SLOTS];

  const int bid = blockIdx.x, tid = threadIdx.x;
  const int wv = tid >> 6, ln = tid & 63;
  const int li = li_p[0], ld = ld_p[0];

  if (bid < NSCANB) {
    // ===== edge scan into private slots =====
    if (tid == 0) l_cnt = 0;
    __syncthreads();
    const int gid = bid * 512 + tid;
    const int stride = NSCANB * 512;
    const int nE4 = nE >> 2;
    const int4* t4 = (const int4*)etrg;
    for (int e4 = gid; e4 < nE4; e4 += stride) {
      int4 t = t4[e4];
      int ev[4] = {t.x, t.y, t.z, t.w};
#pragma unroll
      for (int k = 0; k < 4; ++k) {
        if (ev[k] == li || ev[k] == ld) {
          int e = e4 * 4 + k;
          int p = atomicAdd(&l_cnt, 1);
          if (p < SLOTS) { l_src[p] = esrc[e]; l_trg[p] = ev[k]; l_bin[p] = ebin[e]; }
        }
      }
    }
    if (bid == 0 && tid == 0) {          // tail (nE % 4)
      for (int e = nE4 * 4; e < nE; ++e) {
        int tv = etrg[e];
        if (tv == li || tv == ld) {
          int p = atomicAdd(&l_cnt, 1);
          if (p < SLOTS) { l_src[p] = esrc[e]; l_trg[p] = tv; l_bin[p] = ebin[e]; }
        }
      }
    }
    __syncthreads();
    int c = l_cnt; if (c > SLOTS) c = SLOTS;
    if (tid == 0) bcnt[bid] = c;         // unconditional: overwrites poison
    if (tid < c) {
      bsrc[bid * SLOTS + tid] = l_src[tid];
      btrg[bid * SLOTS + tid] = l_trg[tid];
      bbin[bid * SLOTS + tid] = l_bin[tid];
    }
    if (wv < c && ln < 32)               // dense nf-row copy (wave per match)
      ((float4*)(bnf + (size_t)(bid * SLOTS + wv) * D_IN))[ln] =
          ((const float4*)(nf + (size_t)l_src[wv] * D_IN))[ln];
    return;
  }

  if (bid < SKIP_B) {
    // ===== vsrc + strg for head h (h==0 zeroes K2 flags) =====
    const int h = bid - VSRC_B;
    if (h == 0 && tid < 16) ws_i[tid] = 0;
    const int d = tid & 127, fg = tid >> 7;
    float as = 0.f, at = 0.f;
    for (int f = fg * 8; f < fg * 8 + 8; ++f) {
      float w = Wproj[(h * F_OUT + f) * D_IN + d];
      as = fmaf(a_src[h * F_OUT + f], w, as);
      at = fmaf(a_trg[h * F_OUT + f], w, at);
    }
    s_vp[0][fg][d] = as; s_vp[1][fg][d] = at;
    __syncthreads();
    if (tid < 128)
      vsrc[h * D_IN + tid] =
          s_vp[0][0][tid] + s_vp[0][1][tid] + s_vp[0][2][tid] + s_vp[0][3][tid];
    if (tid >= 128 && tid < 256) {
      int dd = tid - 128;
      s_vp[1][0][dd] = s_vp[1][0][dd] + s_vp[1][1][dd] + s_vp[1][2][dd] + s_vp[1][3][dd];
    }
    if (tid >= 256 && tid < 320) {
      int j = tid - 256;
      ((float4*)s_nf2)[j] = ((const float4*)(nf + (size_t)(j < 32 ? li : ld) * D_IN))[j & 31];
    }
    __syncthreads();
    if (wv < 2) {   // strg[t,h] = nf2[t] . vtrg[h]
      float part = s_nf2[wv * D_IN + ln * 2] * s_vp[1][0][ln * 2]
                 + s_nf2[wv * D_IN + ln * 2 + 1] * s_vp[1][0][ln * 2 + 1];
      part = redw(part);
      if (ln == 0) strg[wv * NH + h] = part;
    }
  } else if (bid < ESC_B) {
    // ===== skipb rows [32p, 32p+32) =====
    const int base = (bid - SKIP_B) * 32;
    if (tid < 64)
      ((float4*)s_nf2)[tid] = ((const float4*)(nf + (size_t)(tid < 32 ? li : ld) * D_IN))[tid & 31];
    __syncthreads();
    for (int rd = 0; rd < 4; ++rd) {
      int r = base + rd * 8 + wv;
      float w0 = Wskip[r * D_IN + ln * 2], w1 = Wskip[r * D_IN + ln * 2 + 1];
      float o0 = w0 * s_nf2[ln * 2] + w1 * s_nf2[ln * 2 + 1];
      float o1 = w0 * s_nf2[D_IN + ln * 2] + w1 * s_nf2[D_IN + ln * 2 + 1];
      o0 = redw(o0); o1 = redw(o1);
      if (ln == 0) { skipb[r] = o0; skipb[256 + r] = o1; }
    }
  } else if (bid < SMS_B) {
    // ===== escall bins [50p, 50p+50) =====
    const int p = bid - ESC_B;
    const int g = tid >> 3, l8 = tid & 7;
    for (int it = g; it < 50 * NH; it += 64) {
      int bin = p * 50 + (it >> 3), hh = it & 7;
      const float* de = demb_g + bin * D_EMB + l8 * 8;
      const float* wd = Wdist + hh * D_EMB + l8 * 8;
      float a = 0.f;
#pragma unroll
      for (int j = 0; j < 8; ++j) a = fmaf(de[j], wd[j], a);
#pragma unroll
      for (int o = 4; o > 0; o >>= 1) a += __shfl_down(a, o, 8);
      if (l8 == 0) escall[bin * NH + hh] = a;
    }
  } else if (bid < PRE1_B) {
    // ===== sms[h] = Wms[h] . ms (wave per head) =====
    const float* wr = Wms + wv * HID;
    float a = 0.f;
#pragma unroll
    for (int m = 0; m < 4; ++m) a = fmaf(wr[ln + 64 * m], ms[ln + 64 * m], a);
    a = redw(a);
    if (ln == 0) sms[wv] = a;
  } else {
    // ===== pre1 rows [16q, 16q+16) =====
    const int q = bid - PRE1_B;
    const int dist = dist_p[0];
    for (int rr = 0; rr < 2; ++rr) {
      int r = q * 16 + wv * 2 + rr;
      const float* w = W1 + (size_t)r * FDIM;
      float a = 0.f;
#pragma unroll
      for (int m = 0; m < 4; ++m) a = fmaf(w[ln + 64 * m], ms[ln + 64 * m], a);
      a = fmaf(w[320 + ln], demb_h[(size_t)dist * D_EMB + ln], a);
      a = redw(a);
      if (ln == 0) pre1[r] = a + b1[r];
    }
  }
}

// =====================================================================
// K2: 8 blocks, one per head h. Block h owns output rows [32h, 32h+32).
// All scan-independent reads issued concurrently at t=0 (1 IC round-trip),
// then: compact -> gather bnf -> scores/agg (LDS) -> proj -> 8-way
// done-word handoff -> MLP -> 8-way final handshake.
// =====================================================================
__global__ __launch_bounds__(512, 1) void finalize_k(
    const int* __restrict__ li_p,
    const float* __restrict__ Wproj, const float* __restrict__ gbias,
    const float* __restrict__ W1, const float* __restrict__ W2,
    const float* __restrict__ b2,
    int* __restrict__ ws_i, float* __restrict__ fb, float* __restrict__ out) {
  int* flag_mlp  = ws_i;
  int* done_proj = ws_i + 8;
  int* bcnt = ws_i + 16;
  int* btrg = ws_i + 1600;
  int* bbin = ws_i + 2944;
  float* vsrc    = fb;
  float* strg    = fb + 1024;
  float* sms     = fb + 1040;
  float* escall  = fb + 1048;
  float* skipb   = fb + 2648;
  float* pre1    = fb + 3160;
  float* out_ws  = fb + 3416;
  float* partial = fb + 3928;
  float* bnf     = fb + 4096;

  __shared__ int s_bc[256], s_sc[256];
  __shared__ int s_mt[NSLOT], s_mb[NSLOT];     // all slot meta, prefetched
  __shared__ int s_sl[CAP], s_tb[CAP], s_bn[CAP];
  __shared__ float s_p[CAP];
  __shared__ float s_den[2];
  __shared__ __align__(16) float s_vs[D_IN];
  __shared__ float s_eh[BINS];                  // escall column for head h
  __shared__ float s_sk0[32], s_sk1[32], s_p1[32];
  __shared__ float s_3[3];                      // sms_h, strg0, strg1
  __shared__ __align__(16) float s_bnf[SNF * D_IN];   // 32 KB
  __shared__ __align__(16) float s_agg[2][D_IN];
  __shared__ __align__(16) float s_out[512];
  __shared__ __align__(16) float s_emb[64];
  __shared__ float s_pr[8];

  const int h = blockIdx.x, tid = threadIdx.x;
  const int wv = tid >> 6, ln = tid & 63;
  const int li = li_p[0];

  // ---- phase 0: everything scan-independent, issued concurrently ----
  float wpA[4], wpB[4], w1e[4], w2v[4];
#pragma unroll
  for (int j = 0; j < 4; ++j) {
    const int r = h * 32 + wv * 4 + j;
    wpA[j] = Wproj[r * D_IN + ln * 2];
    wpB[j] = Wproj[r * D_IN + ln * 2 + 1];
    w1e[j] = W1[(size_t)r * FDIM + HID + ln];
    w2v[j] = W2[r];
  }
  if (tid < 256) s_bc[tid] = (tid < NSCANB) ? bcnt[tid] : 0;
  for (int i = tid; i < NSLOT; i += 512) { s_mt[i] = btrg[i]; s_mb[i] = bbin[i]; }
  if (tid < D_IN) s_vs[tid] = vsrc[h * D_IN + tid];
  if (tid < BINS) s_eh[tid] = escall[tid * NH + h];
  if (tid < 32) {
    s_sk0[tid] = skipb[h * 32 + tid];
    s_sk1[tid] = skipb[256 + h * 32 + tid];
    s_p1[tid]  = pre1[h * 32 + tid];
  }
  if (tid < 3) s_3[tid] = (tid == 0) ? sms[h] : strg[(tid - 1) * NH + h];
  __syncthreads();

  // ---- deterministic compaction: Hillis-Steele prefix scan over 256 ----
  if (tid < 256) s_sc[tid] = s_bc[tid];
  __syncthreads();
  for (int off = 1; off < 256; off <<= 1) {
    int v = 0;
    if (tid < 256 && tid >= off) v = s_sc[tid - off];
    __syncthreads();
    if (tid < 256) s_sc[tid] += v;
    __syncthreads();
  }
  int cnt = s_sc[255]; if (cnt > CAP) cnt = CAP;
  if (tid < NSCANB) {
    int c = s_bc[tid], base = s_sc[tid] - c;
    for (int j = 0; j < c; ++j)
      if (base + j < CAP) s_sl[base + j] = tid * SLOTS + j;
  }
  __syncthreads();
  if (tid < cnt) {
    int sl = s_sl[tid];
    s_tb[tid] = (s_mt[sl] == li) ? 0 : 1;
    s_bn[tid] = s_mb[sl];
  }
  __syncthreads();

  // ---- gather matched bnf rows to LDS (the one scan-dependent RT) ----
  {
    const int lim = (cnt < SNF ? cnt : SNF) * 32;   // float4 count
    float4* dst = (float4*)s_bnf;
    for (int i4 = tid; i4 < lim; i4 += 512)
      dst[i4] = ((const float4*)bnf)[(size_t)s_sl[i4 >> 5] * 32 + (i4 & 31)];
  }
  __syncthreads();

  // ---- scores: exp(leaky_relu(.)); reference's global max cancels ----
  const float sms_h = s_3[0], strg0 = s_3[1], strg1 = s_3[2];
  for (int e = wv; e < cnt; e += 8) {
    float x0, x1;
    if (e < SNF) { x0 = s_bnf[e * D_IN + ln * 2]; x1 = s_bnf[e * D_IN + ln * 2 + 1]; }
    else {
      const float* g = bnf + (size_t)s_sl[e] * D_IN + ln * 2;
      x0 = g[0]; x1 = g[1];
    }
    float part = redw(x0 * s_vs[ln * 2] + x1 * s_vs[ln * 2 + 1]);
    if (ln == 0) {
      float sc = part + (s_tb[e] ? strg1 : strg0) + sms_h + s_eh[s_bn[e]];
      sc = sc > 0.f ? sc : 0.2f * sc;
      s_p[e] = expf(sc);
    }
  }
  __syncthreads();
  if (tid < 2) {
    float d = 1e-16f;
    for (int e = 0; e < cnt; ++e) if (s_tb[e] == (int)tid) d += s_p[e];
    s_den[tid] = d;
  }
  __syncthreads();
  if (tid < cnt) s_p[tid] = s_p[tid] / s_den[s_tb[tid]];
  __syncthreads();
  if (tid < 256) {                        // agg[t,d] for head h (LDS only)
    const int t = tid >> 7, d = tid & 127;
    float a = 0.f;
    for (int e = 0; e < cnt; ++e) {
      if (s_tb[e] == t) {
        float v = (e < SNF) ? s_bnf[e * D_IN + d] : bnf[(size_t)s_sl[e] * D_IN + d];
        a = fmaf(s_p[e], v, a);
      }
    }
    s_agg[t][d] = a;
  }
  __syncthreads();

  // ---- proj: this block's 32 rows from registers ----
#pragma unroll
  for (int j = 0; j < 4; ++j) {
    const int r = h * 32 + wv * 4 + j;
    float o0 = wpA[j] * s_agg[0][ln * 2] + wpB[j] * s_agg[0][ln * 2 + 1];
    float o1 = wpA[j] * s_agg[1][ln * 2] + wpB[j] * s_agg[1][ln * 2 + 1];
    o0 = redw(o0); o1 = redw(o1);
    if (ln == 0) {
      STF(out_ws + r,       o0 + s_sk0[wv * 4 + j]);
      STF(out_ws + 256 + r, o1 + s_sk1[wv * 4 + j]);
    }
  }
  // ---- 8-way proj handoff: distinct done-words, read-spin ----
  vm0();
  __syncthreads();
  if (tid == 0) STF(done_proj + h, 1);
  if (tid < K2GRID)
    while (LDF(done_proj + tid) == 0) __builtin_amdgcn_s_sleep(1);
  __syncthreads();

  // ---- MLP ----
  s_out[tid] = LDF(out_ws + tid);
  __syncthreads();
  if (tid < 64) {
    const int t = tid >> 5, f = tid & 31;
    float s = 0.f;
#pragma unroll
    for (int hh = 0; hh < NH; ++hh) s += s_out[t * 256 + hh * F_OUT + f];
    s = s * 0.125f + gbias[f];
    s_emb[tid] = s > 0.f ? s : expm1f(s);   // ELU
  }
  __syncthreads();
  {
    float bp = 0.f;
#pragma unroll
    for (int j = 0; j < 4; ++j) {
      float acc = redw(w1e[j] * s_emb[ln]);
      if (ln == 0) {
        float h1 = fmaxf(s_p1[wv * 4 + j] + acc, 0.f);
        bp += w2v[j] * h1;
      }
    }
    if (ln == 0) s_pr[wv] = bp;
  }
  __syncthreads();
  if (tid == 0) {
    float bp = 0.f;
#pragma unroll
    for (int w = 0; w < 8; ++w) bp += s_pr[w];
    STF(partial + h, bp);
    vm0();
    int ret = __hip_atomic_fetch_add(flag_mlp, 1, AR, SA);
    if (ret == K2GRID - 1) {                // last block finalizes
      float s = b2[0];
      for (int j = 0; j < K2GRID; ++j) s += LDF(partial + j);
      out[0] = s;
    }
  }
}

extern "C" void kernel_launch(void* const* d_in, const int* in_sizes, int n_in,
                              void* d_out, int out_size, void* d_ws, size_t ws_size,
                              hipStream_t stream) {
  const float* nf     = (const float*)d_in[0];
  const int*   esrc   = (const int*)d_in[1];
  const int*   etrg   = (const int*)d_in[2];
  const int*   ebin   = (const int*)d_in[3];
  const float* ms     = (const float*)d_in[4];
  const int*   li_p   = (const int*)d_in[5];
  const int*   ld_p   = (const int*)d_in[6];
  const int*   dist_p = (const int*)d_in[7];
  const float* Wproj  = (const float*)d_in[8];
  const float* a_src  = (const float*)d_in[9];
  const float* a_trg  = (const float*)d_in[10];
  const float* Wms    = (const float*)d_in[11];
  const float* demb_g = (const float*)d_in[12];
  const float* Wdist  = (const float*)d_in[13];
  const float* Wskip  = (const float*)d_in[14];
  const float* gbias  = (const float*)d_in[15];
  const float* demb_h = (const float*)d_in[16];
  const float* W1     = (const float*)d_in[17];
  const float* b1     = (const float*)d_in[18];
  const float* W2     = (const float*)d_in[19];
  const float* b2     = (const float*)d_in[20];
  const int nE = in_sizes[1];

  int*   ws_i = (int*)d_ws;
  float* fb   = (float*)d_ws + 8192;

  scan_pre_k<<<K1GRID, 512, 0, stream>>>(
      nf, esrc, etrg, ebin, ms, li_p, ld_p, dist_p,
      Wproj, a_src, a_trg, Wms, demb_g, Wdist, Wskip, W1, b1, demb_h,
      nE, ws_i, fb);

  finalize_k<<<K2GRID, 512, 0, stream>>>(
      li_p, Wproj, gbias, W1, W2, b2, ws_i, fb, (float*)d_out);
}